// Round 6
// baseline (289.117 us; speedup 1.0000x reference)
//
#include <hip/hip_runtime.h>
#include <hip/hip_bf16.h>
#include <stdint.h>

#define B_ 2
#define N_ 8192
#define C_ 64
#define K_ 16
#define D_IN 131     // 2C+3
#define XS_STRIDE 168
#define TS 1024
#define L_ 16        // lanes per query
#define QPB 16       // queries per block (256 threads)

typedef __attribute__((ext_vector_type(8))) short short8v;
typedef __attribute__((ext_vector_type(4))) float f32x4;

// sentinel: larger than any real key, but FINITE as f64 (all-ones would be NaN
// and v_min_f64/v_max_f64 drop NaNs -> corrupt list). hi32 = 0x7F7FFFFF = FLT_MAX.
#define SENT_U64 0x7F7FFFFFFFFFFFFFull

__device__ __forceinline__ float sq3(float x, float y, float z) {
#pragma clang fp contract(off)
  return (x * x + y * y) + z * z;
}

__device__ __forceinline__ uint64_t shfl_xor_u64(uint64_t x, int mask) {
  int lo = __shfl_xor((int)(uint32_t)(x & 0xffffffffull), mask, 64);
  int hi = __shfl_xor((int)(uint32_t)(x >> 32), mask, 64);
  return ((uint64_t)(uint32_t)hi << 32) | (uint32_t)lo;
}

__device__ __forceinline__ double shfl_xor_f64(double x, int mask) {
  return __builtin_bit_cast(double, shfl_xor_u64(__builtin_bit_cast(uint64_t, x), mask));
}

__device__ __forceinline__ double pack_key(float d, int idx) {
  return __hiloint2double((int)__float_as_uint(d), idx);
}

__device__ __forceinline__ float key_dist(double k) {
  return __uint_as_float((uint32_t)(__builtin_bit_cast(uint64_t, k) >> 32));
}

// branchless sorted-insert: precondition key < hd[15]; one bubble pass with
// v_min_f64/v_max_f64 (2 insts per stage, 15 stages). Rare path only.
__device__ __forceinline__ void insert16(double* hd, double key) {
  hd[15] = key;
#pragma unroll
  for (int z = 15; z >= 1; --z) {
    double a = hd[z - 1], b = hd[z];
    hd[z - 1] = fmin(a, b);
    hd[z] = fmax(a, b);
  }
}

// ---------------- KNN: 16 queries/block, 16 lanes/query, 1024 blocks ----------------
__global__ __launch_bounds__(256) void knn_kernel(const float* __restrict__ coords,
                                                  int* __restrict__ idxout) {
  __shared__ float4 cl[TS];
  const int t = threadIdx.x;
  const int blk = blockIdx.x;          // 1024 blocks: 512 per batch
  const int bb = blk >> 9;
  const int qbase = (blk & 511) * QPB;
  const float* cb = coords + (size_t)bb * N_ * 3;
  const int ql = t >> 4;               // 0..15: query within block
  const int s = t & 15;                // lane within query group
  const int n = qbase + ql;
  const float qx = cb[n * 3 + 0], qy = cb[n * 3 + 1], qz = cb[n * 3 + 2];
  const float xxq = sq3(qx, qy, qz);

  double hd[16];
#pragma unroll
  for (int i = 0; i < 16; ++i) hd[i] = __builtin_bit_cast(double, SENT_U64);
  float gthr = __uint_as_float(0x7F7FFFFFu);  // FLT_MAX: group prune threshold

  for (int j0 = 0; j0 < N_; j0 += TS) {
    __syncthreads();
#pragma unroll
    for (int i = 0; i < TS / 256; ++i) {
      int j = j0 + t + 256 * i;
      float cx = cb[j * 3 + 0], cy = cb[j * 3 + 1], cz = cb[j * 3 + 2];
      cl[t + 256 * i] = make_float4(cx, cy, cz, sq3(cx, cy, cz));
    }
    __syncthreads();
    for (int i = 0; i < TS / L_; i += 4) {
      const int c0 = s + i * L_;
      float4 cd0 = cl[c0];
      float4 cd1 = cl[c0 + L_];
      float4 cd2 = cl[c0 + 2 * L_];
      float4 cd3 = cl[c0 + 3 * L_];
      float dot0 = fmaf(qz, cd0.z, fmaf(qy, cd0.y, qx * cd0.x));
      float dot1 = fmaf(qz, cd1.z, fmaf(qy, cd1.y, qx * cd1.x));
      float dot2 = fmaf(qz, cd2.z, fmaf(qy, cd2.y, qx * cd2.x));
      float dot3 = fmaf(qz, cd3.z, fmaf(qy, cd3.y, qx * cd3.x));
      float d20, d21, d22, d23;
      {
#pragma clang fp contract(off)
        d20 = (xxq + cd0.w) - 2.0f * dot0;
        d21 = (xxq + cd1.w) - 2.0f * dot1;
        d22 = (xxq + cd2.w) - 2.0f * dot2;
        d23 = (xxq + cd3.w) - 2.0f * dot3;
      }
      d20 = fmaxf(d20, 0.0f);
      d21 = fmaxf(d21, 0.0f);
      d22 = fmaxf(d22, 0.0f);
      d23 = fmaxf(d23, 0.0f);
      float dmin = fminf(fminf(d20, d21), fminf(d22, d23));
      if (__any(dmin <= gthr)) {
        // rare path: exact (dist,idx)-keyed insert, per-lane exec-masked
        double k0 = pack_key(d20, j0 + c0);
        double k1 = pack_key(d21, j0 + c0 + L_);
        double k2 = pack_key(d22, j0 + c0 + 2 * L_);
        double k3 = pack_key(d23, j0 + c0 + 3 * L_);
        if (k0 < hd[15]) insert16(hd, k0);
        if (k1 < hd[15]) insert16(hd, k1);
        if (k2 < hd[15]) insert16(hd, k2);
        if (k3 < hd[15]) insert16(hd, k3);
        // refresh group threshold: min over the 16 lanes of dist(hd[15])
        float h15d = key_dist(hd[15]);
        h15d = fminf(h15d, __shfl_xor(h15d, 1, 64));
        h15d = fminf(h15d, __shfl_xor(h15d, 2, 64));
        h15d = fminf(h15d, __shfl_xor(h15d, 4, 64));
        h15d = fminf(h15d, __shfl_xor(h15d, 8, 64));
        gthr = h15d;
      }
    }
  }

  // merge the 16 per-lane sorted lists -> global top-16 (ascending (dist,idx))
  int* myout = idxout + ((size_t)(bb * N_ + n)) * K_;
#pragma unroll
  for (int r = 0; r < 16; ++r) {
    double v = hd[0];
    v = fmin(v, shfl_xor_f64(v, 1));
    v = fmin(v, shfl_xor_f64(v, 2));
    v = fmin(v, shfl_xor_f64(v, 4));
    v = fmin(v, shfl_xor_f64(v, 8));
    if (__builtin_bit_cast(uint64_t, hd[0]) == __builtin_bit_cast(uint64_t, v)) {
#pragma unroll
      for (int z = 0; z < 15; ++z) hd[z] = hd[z + 1];
      hd[15] = __builtin_bit_cast(double, SENT_U64);
    }
    if (s == 0) myout[r] = (int)(uint32_t)__builtin_bit_cast(uint64_t, v);
  }
}

// ------------- W -> bf16 B-fragment layout: wfrag[nt][ks][lane][j] -------------
__global__ __launch_bounds__(256) void prep_w(const float* __restrict__ W,
                                              __hip_bfloat16* __restrict__ wfrag) {
  int i = blockIdx.x * 256 + threadIdx.x;
  if (i >= 4 * 5 * 64 * 8) return;
  int j = i & 7;
  int l = (i >> 3) & 63;
  int ks = (i >> 9) % 5;
  int nt = (i >> 9) / 5;
  int k = ks * 32 + (l >> 4) * 8 + j;
  int col = nt * 16 + (l & 15);
  float v = (k < D_IN) ? W[k * 64 + col] : 0.0f;
  wfrag[i] = __float2bfloat16(v);
}

// ---------------- stage 2: gather + (16x131)@(131x64) + relu + max_k ----------------
__global__ __launch_bounds__(256) void stage2(const float* __restrict__ coords,
                                              const float* __restrict__ feat,
                                              const int* __restrict__ idxbuf,
                                              const __hip_bfloat16* __restrict__ wfrag,
                                              const float* __restrict__ bias,
                                              float* __restrict__ out) {
  __shared__ __align__(16) __hip_bfloat16 xs[4][16][XS_STRIDE];
  const int t = threadIdx.x;
  const int w = t >> 6;
  const int lane = t & 63;
  const int q = blockIdx.x * 4 + w;
  const int bb = q >> 13;
  const int n = q & (N_ - 1);
  const float* cb = coords + (size_t)bb * N_ * 3;
  const float* fb = feat + (size_t)bb * N_ * C_;
  const int* myidx = idxbuf + (size_t)q * K_;

  float fi = fb[(size_t)n * C_ + lane];
  float qc = (lane < 3) ? cb[n * 3 + lane] : 0.0f;

#pragma unroll
  for (int k = 0; k < K_; ++k) {
    int nb = myidx[k];
    float nf = fb[(size_t)nb * C_ + lane];
    xs[w][k][lane] = __float2bfloat16(fi);
    xs[w][k][C_ + lane] = __float2bfloat16(nf - fi);
    if (lane < 3) {
      xs[w][k][128 + lane] = __float2bfloat16(cb[nb * 3 + lane] - qc);
    } else if (lane < 40) {
      xs[w][k][128 + lane] = __float2bfloat16(0.0f);  // zero-pad d = 131..167
    }
  }
  __syncthreads();

  const int row = lane & 15;   // = output channel within 16-col tile (D's col)
  const int g = lane >> 4;
  short8v a[5];
#pragma unroll
  for (int ks = 0; ks < 5; ++ks)
    a[ks] = *(const short8v*)&xs[w][row][ks * 32 + g * 8];

  const short8v* wf = (const short8v*)wfrag;
#pragma unroll
  for (int nt = 0; nt < 4; ++nt) {
    f32x4 acc = {0.f, 0.f, 0.f, 0.f};
#pragma unroll
    for (int ks = 0; ks < 5; ++ks) {
      short8v bf = wf[(nt * 5 + ks) * 64 + lane];
      acc = __builtin_amdgcn_mfma_f32_16x16x32_bf16(a[ks], bf, acc, 0, 0, 0);
    }
    float bcol = bias[nt * 16 + row];
    float m = fmaxf(fmaxf(fmaxf(acc[0] + bcol, 0.f), fmaxf(acc[1] + bcol, 0.f)),
                    fmaxf(fmaxf(acc[2] + bcol, 0.f), fmaxf(acc[3] + bcol, 0.f)));
    m = fmaxf(m, __shfl_xor(m, 16, 64));
    m = fmaxf(m, __shfl_xor(m, 32, 64));
    if (lane < 16) out[(size_t)q * C_ + nt * 16 + row] = m;
  }
}

extern "C" void kernel_launch(void* const* d_in, const int* in_sizes, int n_in,
                              void* d_out, int out_size, void* d_ws, size_t ws_size,
                              hipStream_t stream) {
  const float* coords = (const float*)d_in[0];
  const float* feat = (const float*)d_in[1];
  const float* W = (const float*)d_in[2];
  const float* bias = (const float*)d_in[3];
  float* out = (float*)d_out;

  int* ws_idx = (int*)d_ws;  // B*N*K ints = 1 MiB
  __hip_bfloat16* wfrag = (__hip_bfloat16*)((char*)d_ws + (size_t)B_ * N_ * K_ * sizeof(int));

  prep_w<<<(4 * 5 * 64 * 8 + 255) / 256, 256, 0, stream>>>(W, wfrag);
  knn_kernel<<<(B_ * N_) / QPB, 256, 0, stream>>>(coords, ws_idx);
  stage2<<<(B_ * N_) / 4, 256, 0, stream>>>(coords, feat, ws_idx, wfrag, bias, out);
}

// Round 10
// 123.062 us; speedup vs baseline: 2.3494x; 2.3494x over previous
//
#include <hip/hip_runtime.h>
#include <hip/hip_bf16.h>
#include <stdint.h>
#include <float.h>

#define B_ 2
#define N_ 8192
#define C_ 64
#define K_ 16
#define D_IN 131     // 2C+3
#define XS_STRIDE 168
#define TS 1024
#define L_ 16        // lanes per query
#define QPB 16       // queries per block (256 threads)
#define CAP 128      // survivor buffer capacity per query

typedef __attribute__((ext_vector_type(8))) short short8v;
typedef __attribute__((ext_vector_type(4))) float f32x4;

// sentinel: larger than any real key, but FINITE as f64 (NaN would break fmin/fmax)
#define SENT_U64 0x7F7FFFFFFFFFFFFFull

__device__ __forceinline__ float sq3(float x, float y, float z) {
#pragma clang fp contract(off)
  return (x * x + y * y) + z * z;
}

__device__ __forceinline__ uint64_t shfl_xor_u64(uint64_t x, int mask) {
  int lo = __shfl_xor((int)(uint32_t)(x & 0xffffffffull), mask, 64);
  int hi = __shfl_xor((int)(uint32_t)(x >> 32), mask, 64);
  return ((uint64_t)(uint32_t)hi << 32) | (uint32_t)lo;
}

__device__ __forceinline__ double shfl_xor_f64(double x, int mask) {
  return __builtin_bit_cast(double, shfl_xor_u64(__builtin_bit_cast(uint64_t, x), mask));
}

__device__ __forceinline__ uint64_t pack_key_u64(float d, int idx) {
  return ((uint64_t)__float_as_uint(d) << 32) | (uint32_t)idx;
}

// branchless sorted-insert: precondition key < hd[15]; 15-stage min/max ladder.
// Runs only on the ~2 inserts/lane in the final select (or rare fallback).
__device__ __forceinline__ void insert16(double* hd, double key) {
  hd[15] = key;
#pragma unroll
  for (int z = 15; z >= 1; --z) {
    double a = hd[z - 1], b = hd[z];
    hd[z - 1] = fmin(a, b);
    hd[z] = fmax(a, b);
  }
}

// ---------------- KNN: two-pass threshold+collect, 16 queries/block ----------------
__global__ __launch_bounds__(256) void knn_kernel(const float* __restrict__ coords,
                                                  int* __restrict__ idxout) {
  __shared__ float4 cl[TS];
  __shared__ unsigned long long sbuf[QPB][CAP];
  __shared__ int scnt[QPB];
  const int t = threadIdx.x;
  const int blk = blockIdx.x;          // 1024 blocks: 512 per batch
  const int bb = blk >> 9;
  const int qbase = (blk & 511) * QPB;
  const float* cb = coords + (size_t)bb * N_ * 3;
  const int ql = t >> 4;               // 0..15: query within block
  const int s = t & 15;                // lane within query group
  const int n = qbase + ql;
  const float qx = cb[n * 3 + 0], qy = cb[n * 3 + 1], qz = cb[n * 3 + 2];
  const float xxq = sq3(qx, qy, qz);

#define DIST4(d20, d21, d22, d23, c0)                                   \
  float4 cd0 = cl[c0];                                                  \
  float4 cd1 = cl[(c0) + L_];                                           \
  float4 cd2 = cl[(c0) + 2 * L_];                                       \
  float4 cd3 = cl[(c0) + 3 * L_];                                       \
  float dot0 = fmaf(qz, cd0.z, fmaf(qy, cd0.y, qx * cd0.x));            \
  float dot1 = fmaf(qz, cd1.z, fmaf(qy, cd1.y, qx * cd1.x));            \
  float dot2 = fmaf(qz, cd2.z, fmaf(qy, cd2.y, qx * cd2.x));            \
  float dot3 = fmaf(qz, cd3.z, fmaf(qy, cd3.y, qx * cd3.x));            \
  {                                                                     \
    _Pragma("clang fp contract(off)")                                   \
    d20 = (xxq + cd0.w) - 2.0f * dot0;                                  \
    d21 = (xxq + cd1.w) - 2.0f * dot1;                                  \
    d22 = (xxq + cd2.w) - 2.0f * dot2;                                  \
    d23 = (xxq + cd3.w) - 2.0f * dot3;                                  \
  }                                                                     \
  d20 = fmaxf(d20, 0.0f);                                               \
  d21 = fmaxf(d21, 0.0f);                                               \
  d22 = fmaxf(d22, 0.0f);                                               \
  d23 = fmaxf(d23, 0.0f);

  // ---- scan 1: branchless per-lane running top-2 (distances only) ----
  float m1 = FLT_MAX, m2 = FLT_MAX;
  if (t < QPB) scnt[t] = 0;
  for (int j0 = 0; j0 < N_; j0 += TS) {
    __syncthreads();
#pragma unroll
    for (int i = 0; i < TS / 256; ++i) {
      int j = j0 + t + 256 * i;
      float cx = cb[j * 3 + 0], cy = cb[j * 3 + 1], cz = cb[j * 3 + 2];
      cl[t + 256 * i] = make_float4(cx, cy, cz, sq3(cx, cy, cz));
    }
    __syncthreads();
    for (int i = 0; i < TS / L_; i += 4) {
      float d20, d21, d22, d23;
      DIST4(d20, d21, d22, d23, s + i * L_)
      // top-2 of the 4 candidates (tree), then merge into (m1,m2)
      float a1 = fminf(d20, d21), b1 = fmaxf(d20, d21);
      float a2 = fminf(d22, d23), b2 = fmaxf(d22, d23);
      float s1 = fminf(a1, a2);
      float s2 = fminf(fmaxf(a1, a2), fminf(b1, b2));
      float n1 = fminf(m1, s1);
      float n2 = fminf(fmaxf(m1, s1), fminf(m2, s2));
      m1 = n1; m2 = n2;
    }
  }

  // ---- threshold: 16th extraction from the group's {m1,m2}x16 = 32 values ----
  // Each extraction removes ALL copies of the current min (over-removal only
  // raises T -> still safe: >=16 distinct candidates have d <= T).
  float A = m1, Bv = m2, T = FLT_MAX;
#pragma unroll
  for (int r = 0; r < 16; ++r) {
    float g = fminf(A, Bv);
    g = fminf(g, __shfl_xor(g, 1, 64));
    g = fminf(g, __shfl_xor(g, 2, 64));
    g = fminf(g, __shfl_xor(g, 4, 64));
    g = fminf(g, __shfl_xor(g, 8, 64));
    T = g;
    A = (A == g) ? FLT_MAX : A;
    Bv = (Bv == g) ? FLT_MAX : Bv;
  }

  // ---- scan 2: collect survivors (d <= T, ties included) into LDS buffer ----
  for (int j0 = 0; j0 < N_; j0 += TS) {
    __syncthreads();
#pragma unroll
    for (int i = 0; i < TS / 256; ++i) {
      int j = j0 + t + 256 * i;
      float cx = cb[j * 3 + 0], cy = cb[j * 3 + 1], cz = cb[j * 3 + 2];
      cl[t + 256 * i] = make_float4(cx, cy, cz, sq3(cx, cy, cz));
    }
    __syncthreads();
    for (int i = 0; i < TS / L_; i += 4) {
      const int c0 = s + i * L_;
      float d20, d21, d22, d23;
      DIST4(d20, d21, d22, d23, c0)
      int p0 = d20 <= T, p1 = d21 <= T, p2 = d22 <= T, p3 = d23 <= T;
      if (__any(p0 | p1 | p2 | p3)) {
        if (p0) { int pos = atomicAdd(&scnt[ql], 1); if (pos < CAP) sbuf[ql][pos] = pack_key_u64(d20, j0 + c0); }
        if (p1) { int pos = atomicAdd(&scnt[ql], 1); if (pos < CAP) sbuf[ql][pos] = pack_key_u64(d21, j0 + c0 + L_); }
        if (p2) { int pos = atomicAdd(&scnt[ql], 1); if (pos < CAP) sbuf[ql][pos] = pack_key_u64(d22, j0 + c0 + 2 * L_); }
        if (p3) { int pos = atomicAdd(&scnt[ql], 1); if (pos < CAP) sbuf[ql][pos] = pack_key_u64(d23, j0 + c0 + 3 * L_); }
      }
    }
  }
  __syncthreads();

  // ---- exact select: per-lane insert16 over survivors, then group merge ----
  double hd[16];
#pragma unroll
  for (int i = 0; i < 16; ++i) hd[i] = __builtin_bit_cast(double, SENT_U64);

  const int cntv = scnt[ql];
  if (cntv > CAP) {
    // overflow fallback (never expected): barrier-free exact rescan from global
    for (int j = s; j < N_; j += L_) {
      float cx = cb[j * 3 + 0], cy = cb[j * 3 + 1], cz = cb[j * 3 + 2];
      float w = sq3(cx, cy, cz);
      float dot = fmaf(qz, cz, fmaf(qy, cy, qx * cx));
      float d2;
      {
#pragma clang fp contract(off)
        d2 = (xxq + w) - 2.0f * dot;
      }
      d2 = fmaxf(d2, 0.0f);
      double k = __builtin_bit_cast(double, pack_key_u64(d2, j));
      if (k < hd[15]) insert16(hd, k);
    }
  } else {
    for (int i = s; i < cntv; i += L_) {
      double k = __builtin_bit_cast(double, (uint64_t)sbuf[ql][i]);
      if (k < hd[15]) insert16(hd, k);
    }
  }

  // merge the 16 per-lane sorted lists -> global top-16 (ascending (dist,idx))
  int* myout = idxout + ((size_t)(bb * N_ + n)) * K_;
#pragma unroll
  for (int r = 0; r < 16; ++r) {
    double v = hd[0];
    v = fmin(v, shfl_xor_f64(v, 1));
    v = fmin(v, shfl_xor_f64(v, 2));
    v = fmin(v, shfl_xor_f64(v, 4));
    v = fmin(v, shfl_xor_f64(v, 8));
    if (__builtin_bit_cast(uint64_t, hd[0]) == __builtin_bit_cast(uint64_t, v)) {
#pragma unroll
      for (int z = 0; z < 15; ++z) hd[z] = hd[z + 1];
      hd[15] = __builtin_bit_cast(double, SENT_U64);
    }
    if (s == 0) myout[r] = (int)(uint32_t)__builtin_bit_cast(uint64_t, v);
  }
}

// ------------- W -> bf16 B-fragment layout: wfrag[nt][ks][lane][j] -------------
__global__ __launch_bounds__(256) void prep_w(const float* __restrict__ W,
                                              __hip_bfloat16* __restrict__ wfrag) {
  int i = blockIdx.x * 256 + threadIdx.x;
  if (i >= 4 * 5 * 64 * 8) return;
  int j = i & 7;
  int l = (i >> 3) & 63;
  int ks = (i >> 9) % 5;
  int nt = (i >> 9) / 5;
  int k = ks * 32 + (l >> 4) * 8 + j;
  int col = nt * 16 + (l & 15);
  float v = (k < D_IN) ? W[k * 64 + col] : 0.0f;
  wfrag[i] = __float2bfloat16(v);
}

// ---------------- stage 2: gather + (16x131)@(131x64) + relu + max_k ----------------
__global__ __launch_bounds__(256) void stage2(const float* __restrict__ coords,
                                              const float* __restrict__ feat,
                                              const int* __restrict__ idxbuf,
                                              const __hip_bfloat16* __restrict__ wfrag,
                                              const float* __restrict__ bias,
                                              float* __restrict__ out) {
  __shared__ __align__(16) __hip_bfloat16 xs[4][16][XS_STRIDE];
  const int t = threadIdx.x;
  const int w = t >> 6;
  const int lane = t & 63;
  const int q = blockIdx.x * 4 + w;
  const int bb = q >> 13;
  const int n = q & (N_ - 1);
  const float* cb = coords + (size_t)bb * N_ * 3;
  const float* fb = feat + (size_t)bb * N_ * C_;
  const int* myidx = idxbuf + (size_t)q * K_;

  float fi = fb[(size_t)n * C_ + lane];
  float qc = (lane < 3) ? cb[n * 3 + lane] : 0.0f;

#pragma unroll
  for (int k = 0; k < K_; ++k) {
    int nb = myidx[k];
    float nf = fb[(size_t)nb * C_ + lane];
    xs[w][k][lane] = __float2bfloat16(fi);
    xs[w][k][C_ + lane] = __float2bfloat16(nf - fi);
    if (lane < 3) {
      xs[w][k][128 + lane] = __float2bfloat16(cb[nb * 3 + lane] - qc);
    } else if (lane < 40) {
      xs[w][k][128 + lane] = __float2bfloat16(0.0f);  // zero-pad d = 131..167
    }
  }
  __syncthreads();

  const int row = lane & 15;   // = output channel within 16-col tile (D's col)
  const int g = lane >> 4;
  short8v a[5];
#pragma unroll
  for (int ks = 0; ks < 5; ++ks)
    a[ks] = *(const short8v*)&xs[w][row][ks * 32 + g * 8];

  const short8v* wf = (const short8v*)wfrag;
#pragma unroll
  for (int nt = 0; nt < 4; ++nt) {
    f32x4 acc = {0.f, 0.f, 0.f, 0.f};
#pragma unroll
    for (int ks = 0; ks < 5; ++ks) {
      short8v bf = wf[(nt * 5 + ks) * 64 + lane];
      acc = __builtin_amdgcn_mfma_f32_16x16x32_bf16(a[ks], bf, acc, 0, 0, 0);
    }
    float bcol = bias[nt * 16 + row];
    float m = fmaxf(fmaxf(fmaxf(acc[0] + bcol, 0.f), fmaxf(acc[1] + bcol, 0.f)),
                    fmaxf(fmaxf(acc[2] + bcol, 0.f), fmaxf(acc[3] + bcol, 0.f)));
    m = fmaxf(m, __shfl_xor(m, 16, 64));
    m = fmaxf(m, __shfl_xor(m, 32, 64));
    if (lane < 16) out[(size_t)q * C_ + nt * 16 + row] = m;
  }
}

extern "C" void kernel_launch(void* const* d_in, const int* in_sizes, int n_in,
                              void* d_out, int out_size, void* d_ws, size_t ws_size,
                              hipStream_t stream) {
  const float* coords = (const float*)d_in[0];
  const float* feat = (const float*)d_in[1];
  const float* W = (const float*)d_in[2];
  const float* bias = (const float*)d_in[3];
  float* out = (float*)d_out;

  int* ws_idx = (int*)d_ws;  // B*N*K ints = 1 MiB
  __hip_bfloat16* wfrag = (__hip_bfloat16*)((char*)d_ws + (size_t)B_ * N_ * K_ * sizeof(int));

  prep_w<<<(4 * 5 * 64 * 8 + 255) / 256, 256, 0, stream>>>(W, wfrag);
  knn_kernel<<<(B_ * N_) / QPB, 256, 0, stream>>>(coords, ws_idx);
  stage2<<<(B_ * N_) / 4, 256, 0, stream>>>(coords, feat, ws_idx, wfrag, bias, out);
}